// Round 1
// baseline (1328.515 us; speedup 1.0000x reference)
//
#include <hip/hip_runtime.h>
#include <hip/hip_bf16.h>

// TinyGRU: x[2048,512] int -> emb[95,48] -> GRU(H=48) -> logits[.,.,95] (+ h_last)
// Strategy:
//  A) xg_table[95][144] = emb @ w_ih^T + b_ih   (token -> input-gate contribution, 55 KB in d_ws)
//  B) recurrence: 1 block (=1 wave) per batch row; lane j<48 owns gate rows {j,j+48,j+96};
//     w_hh rows live in 144 VGPRs; h broadcast via uniform LDS reads.
//     h_t is stashed in the first 48 floats of each 95-wide logits row of d_out.
//  C) logits: block of 256 threads = 256 positions; stage h to LDS; w_out via
//     wave-uniform (scalar) loads; in-place overwrite of own tile only.

#define BATCH 2048
#define SEQ   512
#define HDIM  48
#define VOCAB 95
#define G3    144   // 3*HDIM

__device__ __forceinline__ float sigmoidf_(float x) {
    return 1.0f / (1.0f + __expf(-x));
}

// ---------------- Kernel A: xg_table precompute ----------------
__global__ void xg_precompute(const float* __restrict__ emb,
                              const float* __restrict__ w_ih,
                              const float* __restrict__ b_ih,
                              float* __restrict__ xg) {
    int v = blockIdx.x;    // 0..94
    int g = threadIdx.x;   // 0..143
    const float* e = emb + v * HDIM;      // wave-uniform -> scalar loads
    const float* w = w_ih + g * HDIM;     // per-lane
    float a0 = 0.f, a1 = 0.f, a2 = 0.f, a3 = 0.f;
    #pragma unroll
    for (int k = 0; k < HDIM; k += 4) {
        a0 = fmaf(w[k + 0], e[k + 0], a0);
        a1 = fmaf(w[k + 1], e[k + 1], a1);
        a2 = fmaf(w[k + 2], e[k + 2], a2);
        a3 = fmaf(w[k + 3], e[k + 3], a3);
    }
    xg[v * G3 + g] = b_ih[g] + ((a0 + a1) + (a2 + a3));
}

// ---------------- Kernel B: GRU recurrence ----------------
__global__ __launch_bounds__(64, 2)
void gru_rec(const int* __restrict__ x,
             const float* __restrict__ xg_table,
             const float* __restrict__ w_hh,
             const float* __restrict__ b_hh,
             float* __restrict__ out,       // logits region; rows [pos*95 .. pos*95+47] used as h stash
             float* __restrict__ hidden) {  // [BATCH*HDIM]
    const int row = blockIdx.x;
    const int j   = threadIdx.x;   // lane; active for j<48
    __shared__ float hsh[HDIM];

    // stationary weights: 3 gate rows of w_hh per lane -> 144 VGPRs
    float4 wr[12], wz[12], wn[12];
    float br = 0.f, bz = 0.f, bn = 0.f;
    float hj = 0.f;
    if (j < HDIM) {
        const float4* whr = (const float4*)(w_hh + (j         ) * HDIM);
        const float4* whz = (const float4*)(w_hh + (j +   HDIM) * HDIM);
        const float4* whn = (const float4*)(w_hh + (j + 2*HDIM) * HDIM);
        #pragma unroll
        for (int k = 0; k < 12; ++k) { wr[k] = whr[k]; wz[k] = whz[k]; wn[k] = whn[k]; }
        br = b_hh[j]; bz = b_hh[j + HDIM]; bn = b_hh[j + 2*HDIM];
        hsh[j] = 0.f;
    }
    __syncthreads();

    const int* xrow = x + row * SEQ;
    int tok = xrow[0];
    for (int t = 0; t < SEQ; ++t) {
        int tok_next = (t + 1 < SEQ) ? xrow[t + 1] : 0;
        float hnew = 0.f;
        if (j < HDIM) {
            const float* xg = xg_table + tok * G3;   // L1/L2-resident 55 KB table
            float xr = xg[j], xz = xg[j + HDIM], xn = xg[j + 2*HDIM];
            float accr = br, accz = bz, accn = bn;
            const float4* h4 = (const float4*)hsh;   // uniform addr -> broadcast reads
            #pragma unroll
            for (int k = 0; k < 12; ++k) {
                float4 hh = h4[k];
                accr = fmaf(wr[k].x, hh.x, accr); accr = fmaf(wr[k].y, hh.y, accr);
                accr = fmaf(wr[k].z, hh.z, accr); accr = fmaf(wr[k].w, hh.w, accr);
                accz = fmaf(wz[k].x, hh.x, accz); accz = fmaf(wz[k].y, hh.y, accz);
                accz = fmaf(wz[k].z, hh.z, accz); accz = fmaf(wz[k].w, hh.w, accz);
                accn = fmaf(wn[k].x, hh.x, accn); accn = fmaf(wn[k].y, hh.y, accn);
                accn = fmaf(wn[k].z, hh.z, accn); accn = fmaf(wn[k].w, hh.w, accn);
            }
            float r = sigmoidf_(xr + accr);
            float z = sigmoidf_(xz + accz);
            float n = tanhf(xn + r * accn);
            hnew = (1.0f - z) * n + z * hj;
            hj = hnew;
            // stash h_t in unused head of the 95-wide logits row
            out[((long)(row * SEQ + t)) * VOCAB + j] = hnew;
        }
        __syncthreads();               // single wave: cheap; orders LDS write vs next reads
        if (j < HDIM) hsh[j] = hnew;
        __syncthreads();
        tok = tok_next;
    }
    if (j < HDIM) hidden[row * HDIM + j] = hj;
}

// ---------------- Kernel C: logits projection (in-place over stash) ----------------
__global__ __launch_bounds__(256, 2)
void logits_k(const float* __restrict__ w_out,
              const float* __restrict__ b_out,
              float* __restrict__ out) {
    __shared__ float hsh[256 * HDIM];   // 48 KB
    const long pos0 = (long)blockIdx.x * 256;
    const int tid = threadIdx.x;

    // stage h rows (first 48 floats of each 95-wide row) into LDS, coalesced-ish
    for (int i = tid; i < 256 * HDIM; i += 256) {
        int p = i / HDIM;
        int k = i - p * HDIM;
        hsh[i] = out[(pos0 + p) * VOCAB + k];
    }
    __syncthreads();

    // each thread owns one position; h row -> 48 VGPRs
    float h[HDIM];
    #pragma unroll
    for (int k = 0; k < 12; ++k)
        ((float4*)h)[k] = ((const float4*)(hsh + tid * HDIM))[k];

    float* orow = out + (pos0 + tid) * VOCAB;
    for (int v = 0; v < VOCAB; ++v) {
        const float* w = w_out + v * HDIM;   // wave-uniform -> scalar loads
        float a0 = 0.f, a1 = 0.f, a2 = 0.f, a3 = 0.f;
        #pragma unroll
        for (int k = 0; k < HDIM; k += 4) {
            a0 = fmaf(w[k + 0], h[k + 0], a0);
            a1 = fmaf(w[k + 1], h[k + 1], a1);
            a2 = fmaf(w[k + 2], h[k + 2], a2);
            a3 = fmaf(w[k + 3], h[k + 3], a3);
        }
        orow[v] = b_out[v] + ((a0 + a1) + (a2 + a3));
    }
}

extern "C" void kernel_launch(void* const* d_in, const int* in_sizes, int n_in,
                              void* d_out, int out_size, void* d_ws, size_t ws_size,
                              hipStream_t stream) {
    const int*   x     = (const int*)d_in[0];
    const float* emb   = (const float*)d_in[1];
    const float* w_ih  = (const float*)d_in[2];
    const float* w_hh  = (const float*)d_in[3];
    const float* b_ih  = (const float*)d_in[4];
    const float* b_hh  = (const float*)d_in[5];
    const float* w_out = (const float*)d_in[6];
    const float* b_out = (const float*)d_in[7];

    float* out    = (float*)d_out;
    float* hidden = out + (long)BATCH * SEQ * VOCAB;  // second tuple element
    float* xg     = (float*)d_ws;                     // 95*144*4 = 54,720 B

    xg_precompute<<<VOCAB, G3, 0, stream>>>(emb, w_ih, b_ih, xg);
    gru_rec<<<BATCH, 64, 0, stream>>>(x, xg, w_hh, b_hh, out, hidden);
    logits_k<<<(BATCH * SEQ) / 256, 256, 0, stream>>>(w_out, b_out, out);
}